// Round 18
// baseline (229.982 us; speedup 1.0000x reference)
//
#include <hip/hip_runtime.h>

// LSTM recurrence, 50 steps. B=2048, T=50, F=256, H=256, gates i,f,g,o.
// Phase 0: pack W (bf16 frag order) + quantize U to int8 (per-col scale).
// Phase 1: xz = x@W + b, BM=64 tile (unchanged from r15/16).
// Phase 2: persistent recurrence, 128 blocks x 16 rows, i8 U, kf0-1 LDS.
//          r17/r18: CROSS-STEP SOFTWARE PIPELINE, asm-pinned loads + counted
//          vmcnt(16) waits (T3/T4). S2/S3(t+1) issued right after step t
//          consumes them; XZ(t+1) after the epilogue. All loop vmem is
//          volatile asm (rematerializer-proof) with literal offsets <=3072
//          (r17 failed compile: offset field is 13-bit signed, max 4095 --
//          each stream now uses TWO base pointers, base and base+4096).
//          sched_barrier(0) after each wait (guide rule #18). Final h/c in
//          regs, stored after the loop -> loop has NO compiler vmem.

#define B_ 2048
#define T_ 50
#define F_ 256
#define H_ 256
#define NZ 1024      // 4H

typedef __attribute__((ext_vector_type(8))) short short8;
typedef __attribute__((ext_vector_type(4))) float f32x4;
typedef __attribute__((ext_vector_type(4))) int i32x4;
typedef unsigned short ushort_t;
typedef unsigned int uint_t;

__device__ __forceinline__ ushort_t f2bf(float f) {
    uint_t u = __float_as_uint(f);
    return (ushort_t)((u + 0x7FFFu + ((u >> 16) & 1u)) >> 16);
}
__device__ __forceinline__ uint_t pack2bf(float lo, float hi) {
    return (uint_t)f2bf(lo) | ((uint_t)f2bf(hi) << 16);
}
__device__ __forceinline__ float bf2f(ushort_t u) {
    return __uint_as_float(((uint_t)u) << 16);
}
__device__ __forceinline__ float sigm(float z) {
    return __builtin_amdgcn_rcpf(1.0f + __builtin_amdgcn_exp2f(z * -1.44269504f));
}
__device__ __forceinline__ float tanh_f(float z) {
    return 2.0f * __builtin_amdgcn_rcpf(1.0f + __builtin_amdgcn_exp2f(z * -2.88539008f)) - 1.0f;
}
__device__ __forceinline__ float xz_at(uint2 u, int j) {
    uint_t v = (j < 2) ? u.x : u.y;
    v = (j & 1) ? (v >> 16) : (v & 0xFFFFu);
    return bf2f((ushort_t)v);
}

// -------- pack W: fp32 [256][1024] -> bf16 frag-order panels ---------------
__global__ void pack_w(const float* __restrict__ Wm, ushort_t* __restrict__ W2) {
    int gid  = blockIdx.x * 256 + threadIdx.x;   // 32768 total
    int lane = gid & 63;
    int nf   = (gid >> 6) & 7;
    int w    = (gid >> 9) & 7;
    int kf   = (gid >> 12) & 7;
    int col = (nf >> 1) * 256 + w * 32 + (nf & 1) * 16 + (lane & 15);
    int kb  = kf * 32 + (lane >> 4) * 8;
    short8 v;
#pragma unroll
    for (int e = 0; e < 8; ++e)
        v[e] = (short)f2bf(Wm[(size_t)(kb + e) * NZ + col]);
    *(short8*)(W2 + ((((size_t)kf * 8 + w) * 8 + nf) * 64 + lane) * 8) = v;
}

// -------- U scales: per-column max, one wave per column --------------------
__global__ void pack_scale(const float* __restrict__ Um,
                           float* __restrict__ scq, float* __restrict__ scd) {
    int j    = (blockIdx.x * 256 + threadIdx.x) >> 6;   // 0..1023 (wave id)
    int lane = threadIdx.x & 63;
    float mx = 0.f;
#pragma unroll
    for (int i = 0; i < H_ / 64; ++i)
        mx = fmaxf(mx, fabsf(Um[(size_t)(i * 64 + lane) * NZ + j]));
#pragma unroll
    for (int off = 32; off; off >>= 1)
        mx = fmaxf(mx, __shfl_down(mx, off));
    if (lane == 0) {
        scq[j] = (mx > 0.f) ? (127.0f / mx) : 0.f;
        scd[j] = mx * (1.0f / 16129.0f);      // mx/127^2
    }
}

// -------- pack U: fp32 -> i8 frag order for mfma_i32_16x16x64_i8 ----------
__global__ void pack_u8(const float* __restrict__ Um,
                        const float* __restrict__ scq, char* __restrict__ U8) {
    int gid  = blockIdx.x * 256 + threadIdx.x;   // 16384 total
    int lane = gid & 63;
    int nf   = (gid >> 6) & 7;
    int w    = (gid >> 9) & 7;
    int kf   = (gid >> 12) & 3;
    int col = (nf >> 1) * 256 + w * 32 + (nf & 1) * 16 + (lane & 15);
    int k0  = kf * 64 + (lane >> 4) * 16;
    float qs = scq[col];
    union { char c[16]; int4 v; } u;
#pragma unroll
    for (int e = 0; e < 16; ++e)
        u.c[e] = (char)__float2int_rn(Um[(size_t)(k0 + e) * NZ + col] * qs);
    *(int4*)(U8 + (((size_t)(kf * 8 + w) * 8 + nf) << 10) + (size_t)lane * 16) = u.v;
}

// -------- phase 1: xz[t] = x[:,t,:] @ W + b, BM=64 (unchanged) ------------
__global__ __launch_bounds__(512, 2) void xw_gemm(
    const float* __restrict__ x, const float* __restrict__ bias,
    const ushort_t* __restrict__ W2, ushort_t* __restrict__ xz2) {
    __shared__ __align__(16) ushort_t As[64 * 256];   // 32 KB, swizzled

    const int tid = threadIdx.x;
    const int t = blockIdx.x, rb = blockIdx.y, row0 = rb * 64;
    const int w = tid >> 6, lane = tid & 63, r16 = lane & 15, q = lane >> 4;

    {
        int sr = tid >> 4, sc = tid & 15;
#pragma unroll
        for (int rr = 0; rr < 64; rr += 32) {
            const float* xp = x + ((size_t)(row0 + rr + sr) * T_ + t) * F_ + sc * 16;
            float4 f0 = *(const float4*)(xp + 0);
            float4 f1 = *(const float4*)(xp + 4);
            float4 f2 = *(const float4*)(xp + 8);
            float4 f3 = *(const float4*)(xp + 12);
            uint4 u0 = {pack2bf(f0.x, f0.y), pack2bf(f0.z, f0.w),
                        pack2bf(f1.x, f1.y), pack2bf(f1.z, f1.w)};
            uint4 u1 = {pack2bf(f2.x, f2.y), pack2bf(f2.z, f2.w),
                        pack2bf(f3.x, f3.y), pack2bf(f3.z, f3.w)};
            int c0 = (2 * sc) ^ (sr & 7), c1 = (2 * sc + 1) ^ (sr & 7);
            *(uint4*)&As[(rr + sr) * 256 + c0 * 8] = u0;
            *(uint4*)&As[(rr + sr) * 256 + c1 * 8] = u1;
        }
    }
    float bcol[8];
#pragma unroll
    for (int nf = 0; nf < 8; ++nf)
        bcol[nf] = bias[(nf >> 1) * 256 + w * 32 + (nf & 1) * 16 + r16];
    __syncthreads();

    f32x4 acc[4][8];
#pragma unroll
    for (int m = 0; m < 4; ++m)
#pragma unroll
        for (int nf = 0; nf < 8; ++nf) acc[m][nf] = (f32x4){0.f, 0.f, 0.f, 0.f};
    short8 SB0[8], SB1[8];

#define LOADB(BUF, KF_)                                                       \
    _Pragma("unroll") for (int nf = 0; nf < 8; ++nf)                          \
        BUF[nf] = *(const short8*)(W2 +                                       \
            ((((size_t)(KF_) * 8 + w) * 8 + nf) * 64 + lane) * 8);

#define MF1(BUF, KF_)                                                         \
    do {                                                                      \
        _Pragma("unroll") for (int m = 0; m < 4; ++m) {                       \
            short8 a_ = *(const short8*)&As[(m * 16 + r16) * 256              \
                                            + (((KF_)*4 + q) ^ (r16 & 7)) * 8];\
            _Pragma("unroll") for (int nf = 0; nf < 8; ++nf)                  \
                acc[m][nf] = __builtin_amdgcn_mfma_f32_16x16x32_bf16(         \
                    a_, BUF[nf], acc[m][nf], 0, 0, 0);                        \
        }                                                                     \
    } while (0)

    LOADB(SB0, 0); LOADB(SB1, 1);
    MF1(SB0, 0); LOADB(SB0, 2);
    MF1(SB1, 1); LOADB(SB1, 3);
    MF1(SB0, 2); LOADB(SB0, 4);
    MF1(SB1, 3); LOADB(SB1, 5);
    MF1(SB0, 4); LOADB(SB0, 6);
    MF1(SB1, 5); LOADB(SB1, 7);
    MF1(SB0, 6);
    MF1(SB1, 7);

    uint2* outp = (uint2*)xz2;
#pragma unroll
    for (int m = 0; m < 4; ++m) {
        const size_t cb = (((size_t)t * 64 + (size_t)(rb * 2 + (m >> 1))) * 8 + w) * 16
                        + (size_t)(m & 1) * 8;
#pragma unroll
        for (int nf = 0; nf < 8; ++nf) {
            f32x4 a = acc[m][nf];
            float b = bcol[nf];
            uint2 o = {pack2bf(a[0] + b, a[1] + b), pack2bf(a[2] + b, a[3] + b)};
            outp[(cb + nf) * 64 + lane] = o;
        }
    }
#undef LOADB
#undef MF1
}

// -------- phase 2: persistent recurrence, asm-pipelined stream -------------
__global__ __launch_bounds__(512, 1) void lstm_rec(
    const char* __restrict__ U8, const float* __restrict__ scd,
    const ushort_t* __restrict__ xz2, float* __restrict__ outp, int T) {
    __shared__ __align__(16) char UL[131072];     // U kf0,kf1 i8 (128 KB)
    __shared__ __align__(16) char hbc[2][4096];   // h i8 dbuf (2 x 4 KB)

    const int tid = threadIdx.x;
    const int rb = blockIdx.x, row0 = rb * 16;
    const int w = tid >> 6, lane = tid & 63, r16 = lane & 15, q = lane >> 4;

#pragma unroll
    for (int i = 0; i < 16; ++i) {
        int off = i * 8192 + tid * 16;
        __builtin_amdgcn_global_load_lds(
            (const __attribute__((address_space(1))) void*)(U8 + off),
            (__attribute__((address_space(3))) void*)(UL + off),
            16, 0, 0);
    }
    *(uint2*)&hbc[0][tid * 8] = (uint2){0, 0};

    float d[8];
#pragma unroll
    for (int nf = 0; nf < 8; ++nf)
        d[nf] = scd[(nf >> 1) * 256 + w * 32 + (nf & 1) * 16 + r16];

    // per-lane stream bases; offset field is 13-bit signed (<=4095), so each
    // 8KB panel uses two bases (lo: nf 0-3, hi: nf 4-7), offsets 0..3072.
    const char* baseS2  = U8 + (((size_t)(2 * 8 + w) * 8) << 10) + (size_t)lane * 16;
    const char* baseS2h = baseS2 + 4096;
    const char* baseS3  = U8 + (((size_t)(3 * 8 + w) * 8) << 10) + (size_t)lane * 16;
    const char* baseS3h = baseS3 + 4096;
    // xz base (k stride 512B -> offsets 0..3584 ok); advances 4MB per t
    const size_t cbconst = (((size_t)(rb >> 1)) * 8 + w) * 16 + (size_t)(rb & 1) * 8;
    const char* xzcur = (const char*)((const uint2*)xz2 + cbconst * 64 + lane);

    i32x4 S2[8], S3[8];
    uint2 XZ[8];

    // ---- asm load issue macros (volatile -> position & order pinned) ----
#define ISSUE_S2()                                                            \
    do {                                                                      \
        asm volatile("global_load_dwordx4 %0, %1, off"              : "=v"(S2[0]) : "v"(baseS2));  \
        asm volatile("global_load_dwordx4 %0, %1, off offset:1024"  : "=v"(S2[1]) : "v"(baseS2));  \
        asm volatile("global_load_dwordx4 %0, %1, off offset:2048"  : "=v"(S2[2]) : "v"(baseS2));  \
        asm volatile("global_load_dwordx4 %0, %1, off offset:3072"  : "=v"(S2[3]) : "v"(baseS2));  \
        asm volatile("global_load_dwordx4 %0, %1, off"              : "=v"(S2[4]) : "v"(baseS2h)); \
        asm volatile("global_load_dwordx4 %0, %1, off offset:1024"  : "=v"(S2[5]) : "v"(baseS2h)); \
        asm volatile("global_load_dwordx4 %0, %1, off offset:2048"  : "=v"(S2[6]) : "v"(baseS2h)); \
        asm volatile("global_load_dwordx4 %0, %1, off offset:3072"  : "=v"(S2[7]) : "v"(baseS2h)); \
    } while (0)
#define ISSUE_S3()                                                            \
    do {                                                                      \
        asm volatile("global_load_dwordx4 %0, %1, off"              : "=v"(S3[0]) : "v"(baseS3));  \
        asm volatile("global_load_dwordx4 %0, %1, off offset:1024"  : "=v"(S3[1]) : "v"(baseS3));  \
        asm volatile("global_load_dwordx4 %0, %1, off offset:2048"  : "=v"(S3[2]) : "v"(baseS3));  \
        asm volatile("global_load_dwordx4 %0, %1, off offset:3072"  : "=v"(S3[3]) : "v"(baseS3));  \
        asm volatile("global_load_dwordx4 %0, %1, off"              : "=v"(S3[4]) : "v"(baseS3h)); \
        asm volatile("global_load_dwordx4 %0, %1, off offset:1024"  : "=v"(S3[5]) : "v"(baseS3h)); \
        asm volatile("global_load_dwordx4 %0, %1, off offset:2048"  : "=v"(S3[6]) : "v"(baseS3h)); \
        asm volatile("global_load_dwordx4 %0, %1, off offset:3072"  : "=v"(S3[7]) : "v"(baseS3h)); \
    } while (0)
#define ISSUE_XZ(P_)                                                          \
    do {                                                                      \
        asm volatile("global_load_dwordx2 %0, %1, off"              : "=v"(XZ[0]) : "v"(P_)); \
        asm volatile("global_load_dwordx2 %0, %1, off offset:512"   : "=v"(XZ[1]) : "v"(P_)); \
        asm volatile("global_load_dwordx2 %0, %1, off offset:1024"  : "=v"(XZ[2]) : "v"(P_)); \
        asm volatile("global_load_dwordx2 %0, %1, off offset:1536"  : "=v"(XZ[3]) : "v"(P_)); \
        asm volatile("global_load_dwordx2 %0, %1, off offset:2048"  : "=v"(XZ[4]) : "v"(P_)); \
        asm volatile("global_load_dwordx2 %0, %1, off offset:2560"  : "=v"(XZ[5]) : "v"(P_)); \
        asm volatile("global_load_dwordx2 %0, %1, off offset:3072"  : "=v"(XZ[6]) : "v"(P_)); \
        asm volatile("global_load_dwordx2 %0, %1, off offset:3584"  : "=v"(XZ[7]) : "v"(P_)); \
    } while (0)
#define VMWAIT16()                                                            \
    do { asm volatile("s_waitcnt vmcnt(16)" ::: "memory");                    \
         __builtin_amdgcn_sched_barrier(0); } while (0)

#define AFRAG8(HP_, KF_)                                                      \
    (*(const i32x4*)&(HP_)[r16 * 256 + ((((KF_)*4 + q) ^ (r16 & 7)) << 4)])

    i32x4 acc[8];
    f32x4 creg[2];
    creg[0] = (f32x4){0.f, 0.f, 0.f, 0.f};
    creg[1] = (f32x4){0.f, 0.f, 0.f, 0.f};
    f32x4 hreg[2];   // last step's h (for final output)

    // prologue: prime the pipe (queue: S2,S3,XZ); sync drains everything
    ISSUE_S2();
    ISSUE_S3();
    ISSUE_XZ(xzcur);
    int cur = 0;
    __syncthreads();   // UL + hbc[0] ready; all prefetches landed

#pragma clang loop unroll(disable)
    for (int t = 0; t < T; ++t) {
        const char* hc = hbc[cur];
        char* hn = hbc[cur ^ 1];

#pragma unroll
        for (int nf = 0; nf < 8; ++nf) acc[nf] = (i32x4){0, 0, 0, 0};

        // kf0,kf1 from LDS (no vmem)
        __builtin_amdgcn_s_setprio(1);
#pragma unroll
        for (int kf = 0; kf < 2; ++kf) {
            i32x4 a = AFRAG8(hc, kf);
#pragma unroll
            for (int nf = 0; nf < 8; ++nf) {
                i32x4 b = *(const i32x4*)&UL[(((size_t)(kf * 8 + w) * 8 + nf) << 10)
                                             + (size_t)lane * 16];
                acc[nf] = __builtin_amdgcn_mfma_i32_16x16x64_i8(a, b, acc[nf], 0, 0, 0);
            }
        }
        __builtin_amdgcn_s_setprio(0);

        // consume S2 (queue S2,S3,XZ -> wait 16), then re-issue for t+1
        VMWAIT16();
        {
            i32x4 a2 = AFRAG8(hc, 2);
            __builtin_amdgcn_s_setprio(1);
#pragma unroll
            for (int nf = 0; nf < 8; ++nf)
                acc[nf] = __builtin_amdgcn_mfma_i32_16x16x64_i8(a2, S2[nf], acc[nf], 0, 0, 0);
            __builtin_amdgcn_s_setprio(0);
        }
        ISSUE_S2();                       // queue: S3,XZ,S2'

        // consume S3 (wait 16), re-issue for t+1
        VMWAIT16();
        {
            i32x4 a3 = AFRAG8(hc, 3);
            __builtin_amdgcn_s_setprio(1);
#pragma unroll
            for (int nf = 0; nf < 8; ++nf)
                acc[nf] = __builtin_amdgcn_mfma_i32_16x16x64_i8(a3, S3[nf], acc[nf], 0, 0, 0);
            __builtin_amdgcn_s_setprio(0);
        }
        ISSUE_S3();                       // queue: XZ,S2',S3'

        // consume XZ(t) in epilogue (wait 16)
        VMWAIT16();
#pragma unroll
        for (int hf = 0; hf < 2; ++hf) {
#pragma unroll
            for (int j = 0; j < 4; ++j) {
                float zi = (float)acc[0 + hf][j] * d[0 + hf] + xz_at(XZ[0 + hf], j);
                float zf = (float)acc[2 + hf][j] * d[2 + hf] + xz_at(XZ[2 + hf], j);
                float zg = (float)acc[4 + hf][j] * d[4 + hf] + xz_at(XZ[4 + hf], j);
                float zo = (float)acc[6 + hf][j] * d[6 + hf] + xz_at(XZ[6 + hf], j);
                float ig = sigm(zi);
                float fg = sigm(zf);
                float gg = tanh_f(zg);
                float og = sigm(zo);
                float cn = fg * creg[hf][j] + ig * gg;
                float hv = og * tanh_f(cn);
                creg[hf][j] = cn;
                hreg[hf][j] = hv;
                int row = q * 4 + j;
                int ch  = w * 32 + hf * 16 + r16;
                hn[row * 256 + (((ch >> 4) ^ (row & 7)) << 4) + (ch & 15)] =
                    (char)__float2int_rn(hv * 127.0f);
            }
        }

        // XZ(t+1): advance base, issue last (queue: S2',S3',XZ')
        xzcur += (size_t)8192 * 64 * 8;   // 4 MB per t
        ISSUE_XZ(xzcur);

        // raw barrier: drain LDS h-writes only; 24 global loads stay in flight
        asm volatile("s_waitcnt lgkmcnt(0)" ::: "memory");
        __builtin_amdgcn_s_barrier();
        cur ^= 1;
    }

    // final output from registers (exact h of last step + exact c)
#pragma unroll
    for (int hf = 0; hf < 2; ++hf) {
#pragma unroll
        for (int j = 0; j < 4; ++j) {
            int row = q * 4 + j;
            int ch  = w * 32 + hf * 16 + r16;
            size_t oi = (size_t)(row0 + row) * H_ + ch;
            outp[oi] = hreg[hf][j];
            outp[(size_t)B_ * H_ + oi] = creg[hf][j];
        }
    }
#undef ISSUE_S2
#undef ISSUE_S3
#undef ISSUE_XZ
#undef VMWAIT16
#undef AFRAG8
}

extern "C" void kernel_launch(void* const* d_in, const int* in_sizes, int n_in,
                              void* d_out, int out_size, void* d_ws, size_t ws_size,
                              hipStream_t stream) {
    const float* x    = (const float*)d_in[0];
    const float* Wm   = (const float*)d_in[1];
    const float* Um   = (const float*)d_in[2];
    const float* bias = (const float*)d_in[3];

    // ws bytes: W2 @0 (512K) | U8 @512K (256K) | scq @768K (4K) |
    //           scd @772K (4K) | xz2 @776K (210 MB)      (ws = 400 MiB)
    ushort_t* W2  = (ushort_t*)d_ws;
    char*     U8  = (char*)d_ws + 524288;
    float*    scq = (float*)((char*)d_ws + 786432);
    float*    scd = (float*)((char*)d_ws + 790528);
    ushort_t* xz2 = (ushort_t*)((char*)d_ws + 794624);

    pack_w<<<128, 256, 0, stream>>>(Wm, W2);
    pack_scale<<<256, 256, 0, stream>>>(Um, scq, scd);
    pack_u8<<<64, 256, 0, stream>>>(Um, scq, U8);
    dim3 g1(T_, 32);
    xw_gemm<<<g1, 512, 0, stream>>>(x, bias, W2, xz2);
    lstm_rec<<<128, 512, 0, stream>>>(U8, scd, xz2, (float*)d_out, T_);
}

// Round 19
// 224.102 us; speedup vs baseline: 1.0262x; 1.0262x over previous
//
#include <hip/hip_runtime.h>

// LSTM recurrence, 50 steps. B=2048, T=50, F=256, H=256, gates i,f,g,o.
// Phase 0: pack W (bf16 frag order) + quantize U to int8 (per-col scale).
// Phase 1: xz = x@W + b, BM=64 tile (unchanged).
// Phase 2: persistent recurrence, 128 blocks x 16 rows. U i8: kf0-1 in LDS
//          (128 KB), kf2-3 in AGPRs (64 AGPR/thread = 128 KB/block) -- r19.
//          r14-r18 proved step time tracks streamed-bytes/CU (bf16 384KB ->
//          4.9us, i8 128KB -> 2.6us, schedule-insensitive +-5%): a single
//          block cannot pull L2 faster, so the stream is removed entirely.
//          This fits where r11 spilled: i8 halves the panel to 64 AGPR +
//          ~120 VGPR = 184 < 256 unified regs at 2 waves/SIMD. "+a" pins
//          (r11-proven construct) once at load + loop-carried per iteration.
//          Per-step VMEM = one 32KB/block XZ prefetch (one step ahead).

#define B_ 2048
#define T_ 50
#define F_ 256
#define H_ 256
#define NZ 1024      // 4H

typedef __attribute__((ext_vector_type(8))) short short8;
typedef __attribute__((ext_vector_type(4))) float f32x4;
typedef __attribute__((ext_vector_type(4))) int i32x4;
typedef unsigned short ushort_t;
typedef unsigned int uint_t;

__device__ __forceinline__ ushort_t f2bf(float f) {
    uint_t u = __float_as_uint(f);
    return (ushort_t)((u + 0x7FFFu + ((u >> 16) & 1u)) >> 16);
}
__device__ __forceinline__ uint_t pack2bf(float lo, float hi) {
    return (uint_t)f2bf(lo) | ((uint_t)f2bf(hi) << 16);
}
__device__ __forceinline__ float bf2f(ushort_t u) {
    return __uint_as_float(((uint_t)u) << 16);
}
__device__ __forceinline__ float sigm(float z) {
    return __builtin_amdgcn_rcpf(1.0f + __builtin_amdgcn_exp2f(z * -1.44269504f));
}
__device__ __forceinline__ float tanh_f(float z) {
    return 2.0f * __builtin_amdgcn_rcpf(1.0f + __builtin_amdgcn_exp2f(z * -2.88539008f)) - 1.0f;
}
__device__ __forceinline__ float xz_at(uint2 u, int j) {
    uint_t v = (j < 2) ? u.x : u.y;
    v = (j & 1) ? (v >> 16) : (v & 0xFFFFu);
    return bf2f((ushort_t)v);
}

// -------- pack W: fp32 [256][1024] -> bf16 frag-order panels ---------------
__global__ void pack_w(const float* __restrict__ Wm, ushort_t* __restrict__ W2) {
    int gid  = blockIdx.x * 256 + threadIdx.x;   // 32768 total
    int lane = gid & 63;
    int nf   = (gid >> 6) & 7;
    int w    = (gid >> 9) & 7;
    int kf   = (gid >> 12) & 7;
    int col = (nf >> 1) * 256 + w * 32 + (nf & 1) * 16 + (lane & 15);
    int kb  = kf * 32 + (lane >> 4) * 8;
    short8 v;
#pragma unroll
    for (int e = 0; e < 8; ++e)
        v[e] = (short)f2bf(Wm[(size_t)(kb + e) * NZ + col]);
    *(short8*)(W2 + ((((size_t)kf * 8 + w) * 8 + nf) * 64 + lane) * 8) = v;
}

// -------- U scales: per-column max, one wave per column --------------------
__global__ void pack_scale(const float* __restrict__ Um,
                           float* __restrict__ scq, float* __restrict__ scd) {
    int j    = (blockIdx.x * 256 + threadIdx.x) >> 6;   // 0..1023 (wave id)
    int lane = threadIdx.x & 63;
    float mx = 0.f;
#pragma unroll
    for (int i = 0; i < H_ / 64; ++i)
        mx = fmaxf(mx, fabsf(Um[(size_t)(i * 64 + lane) * NZ + j]));
#pragma unroll
    for (int off = 32; off; off >>= 1)
        mx = fmaxf(mx, __shfl_down(mx, off));
    if (lane == 0) {
        scq[j] = (mx > 0.f) ? (127.0f / mx) : 0.f;
        scd[j] = mx * (1.0f / 16129.0f);      // mx/127^2
    }
}

// -------- pack U: fp32 -> i8 frag order for mfma_i32_16x16x64_i8 ----------
__global__ void pack_u8(const float* __restrict__ Um,
                        const float* __restrict__ scq, char* __restrict__ U8) {
    int gid  = blockIdx.x * 256 + threadIdx.x;   // 16384 total
    int lane = gid & 63;
    int nf   = (gid >> 6) & 7;
    int w    = (gid >> 9) & 7;
    int kf   = (gid >> 12) & 3;
    int col = (nf >> 1) * 256 + w * 32 + (nf & 1) * 16 + (lane & 15);
    int k0  = kf * 64 + (lane >> 4) * 16;
    float qs = scq[col];
    union { char c[16]; int4 v; } u;
#pragma unroll
    for (int e = 0; e < 16; ++e)
        u.c[e] = (char)__float2int_rn(Um[(size_t)(k0 + e) * NZ + col] * qs);
    *(int4*)(U8 + (((size_t)(kf * 8 + w) * 8 + nf) << 10) + (size_t)lane * 16) = u.v;
}

// -------- phase 1: xz[t] = x[:,t,:] @ W + b, BM=64 (unchanged) ------------
__global__ __launch_bounds__(512, 2) void xw_gemm(
    const float* __restrict__ x, const float* __restrict__ bias,
    const ushort_t* __restrict__ W2, ushort_t* __restrict__ xz2) {
    __shared__ __align__(16) ushort_t As[64 * 256];   // 32 KB, swizzled

    const int tid = threadIdx.x;
    const int t = blockIdx.x, rb = blockIdx.y, row0 = rb * 64;
    const int w = tid >> 6, lane = tid & 63, r16 = lane & 15, q = lane >> 4;

    {
        int sr = tid >> 4, sc = tid & 15;
#pragma unroll
        for (int rr = 0; rr < 64; rr += 32) {
            const float* xp = x + ((size_t)(row0 + rr + sr) * T_ + t) * F_ + sc * 16;
            float4 f0 = *(const float4*)(xp + 0);
            float4 f1 = *(const float4*)(xp + 4);
            float4 f2 = *(const float4*)(xp + 8);
            float4 f3 = *(const float4*)(xp + 12);
            uint4 u0 = {pack2bf(f0.x, f0.y), pack2bf(f0.z, f0.w),
                        pack2bf(f1.x, f1.y), pack2bf(f1.z, f1.w)};
            uint4 u1 = {pack2bf(f2.x, f2.y), pack2bf(f2.z, f2.w),
                        pack2bf(f3.x, f3.y), pack2bf(f3.z, f3.w)};
            int c0 = (2 * sc) ^ (sr & 7), c1 = (2 * sc + 1) ^ (sr & 7);
            *(uint4*)&As[(rr + sr) * 256 + c0 * 8] = u0;
            *(uint4*)&As[(rr + sr) * 256 + c1 * 8] = u1;
        }
    }
    float bcol[8];
#pragma unroll
    for (int nf = 0; nf < 8; ++nf)
        bcol[nf] = bias[(nf >> 1) * 256 + w * 32 + (nf & 1) * 16 + r16];
    __syncthreads();

    f32x4 acc[4][8];
#pragma unroll
    for (int m = 0; m < 4; ++m)
#pragma unroll
        for (int nf = 0; nf < 8; ++nf) acc[m][nf] = (f32x4){0.f, 0.f, 0.f, 0.f};
    short8 SB0[8], SB1[8];

#define LOADB(BUF, KF_)                                                       \
    _Pragma("unroll") for (int nf = 0; nf < 8; ++nf)                          \
        BUF[nf] = *(const short8*)(W2 +                                       \
            ((((size_t)(KF_) * 8 + w) * 8 + nf) * 64 + lane) * 8);

#define MF1(BUF, KF_)                                                         \
    do {                                                                      \
        _Pragma("unroll") for (int m = 0; m < 4; ++m) {                       \
            short8 a_ = *(const short8*)&As[(m * 16 + r16) * 256              \
                                            + (((KF_)*4 + q) ^ (r16 & 7)) * 8];\
            _Pragma("unroll") for (int nf = 0; nf < 8; ++nf)                  \
                acc[m][nf] = __builtin_amdgcn_mfma_f32_16x16x32_bf16(         \
                    a_, BUF[nf], acc[m][nf], 0, 0, 0);                        \
        }                                                                     \
    } while (0)

    LOADB(SB0, 0); LOADB(SB1, 1);
    MF1(SB0, 0); LOADB(SB0, 2);
    MF1(SB1, 1); LOADB(SB1, 3);
    MF1(SB0, 2); LOADB(SB0, 4);
    MF1(SB1, 3); LOADB(SB1, 5);
    MF1(SB0, 4); LOADB(SB0, 6);
    MF1(SB1, 5); LOADB(SB1, 7);
    MF1(SB0, 6);
    MF1(SB1, 7);

    uint2* outp = (uint2*)xz2;
#pragma unroll
    for (int m = 0; m < 4; ++m) {
        const size_t cb = (((size_t)t * 64 + (size_t)(rb * 2 + (m >> 1))) * 8 + w) * 16
                        + (size_t)(m & 1) * 8;
#pragma unroll
        for (int nf = 0; nf < 8; ++nf) {
            f32x4 a = acc[m][nf];
            float b = bcol[nf];
            uint2 o = {pack2bf(a[0] + b, a[1] + b), pack2bf(a[2] + b, a[3] + b)};
            outp[(cb + nf) * 64 + lane] = o;
        }
    }
#undef LOADB
#undef MF1
}

// -------- phase 2: persistent recurrence, kf2-3 in AGPRs ------------------
__global__ __launch_bounds__(512, 1) void lstm_rec(
    const char* __restrict__ U8, const float* __restrict__ scd,
    const ushort_t* __restrict__ xz2, float* __restrict__ outp, int T) {
    __shared__ __align__(16) char UL[131072];     // U kf0,kf1 i8 (128 KB)
    __shared__ __align__(16) char hbc[2][4096];   // h i8 dbuf (2 x 4 KB)

    const int tid = threadIdx.x;
    const int rb = blockIdx.x, row0 = rb * 16;
    const int w = tid >> 6, lane = tid & 63, r16 = lane & 15, q = lane >> 4;

    // kf0-1 -> LDS (linear 128 KB)
#pragma unroll
    for (int i = 0; i < 16; ++i) {
        int off = i * 8192 + tid * 16;
        __builtin_amdgcn_global_load_lds(
            (const __attribute__((address_space(1))) void*)(U8 + off),
            (__attribute__((address_space(3))) void*)(UL + off),
            16, 0, 0);
    }
    *(uint2*)&hbc[0][tid * 8] = (uint2){0, 0};

    // kf2-3 -> AGPRs (64 AGPR/thread = 128 KB/block), pinned vs remat
    i32x4 UA2[8], UA3[8];
#pragma unroll
    for (int nf = 0; nf < 8; ++nf)
        UA2[nf] = *(const i32x4*)(U8 + (((size_t)(2 * 8 + w) * 8 + nf) << 10)
                                  + (size_t)lane * 16);
#pragma unroll
    for (int nf = 0; nf < 8; ++nf)
        UA3[nf] = *(const i32x4*)(U8 + (((size_t)(3 * 8 + w) * 8 + nf) << 10)
                                  + (size_t)lane * 16);
#pragma unroll
    for (int nf = 0; nf < 8; ++nf) {
        asm volatile("" : "+a"(UA2[nf]));
        asm volatile("" : "+a"(UA3[nf]));
    }

    float d[8];
#pragma unroll
    for (int nf = 0; nf < 8; ++nf)
        d[nf] = scd[(nf >> 1) * 256 + w * 32 + (nf & 1) * 16 + r16];

    const uint2* xzp = (const uint2*)xz2;
    const size_t cbconst = (((size_t)(rb >> 1)) * 8 + w) * 16 + (size_t)(rb & 1) * 8;
    const uint2* xzb = xzp + cbconst * 64 + lane;
    const size_t TSTRIDE = (size_t)8192 * 64;

#define AFRAG8(HP_, KF_)                                                      \
    (*(const i32x4*)&(HP_)[r16 * 256 + ((((KF_)*4 + q) ^ (r16 & 7)) << 4)])

    i32x4 acc[8];
    f32x4 creg[2];
    creg[0] = (f32x4){0.f, 0.f, 0.f, 0.f};
    creg[1] = (f32x4){0.f, 0.f, 0.f, 0.f};
    f32x4 hreg[2];

    // XZ(0) loaded ahead; steady state: XZ(t+1) prefetched during step t
    uint2 XZ[8];
#pragma unroll
    for (int k = 0; k < 8; ++k) XZ[k] = xzb[(size_t)k * 64];

    int cur = 0;
    __syncthreads();

#pragma clang loop unroll(disable)
    for (int t = 0; t < T; ++t) {
        const char* hc = hbc[cur];
        char* hn = hbc[cur ^ 1];

        // loop-carried AGPR pins (opaque defs -> remat impossible)
#pragma unroll
        for (int nf = 0; nf < 8; ++nf) {
            asm volatile("" : "+a"(UA2[nf]));
            asm volatile("" : "+a"(UA3[nf]));
        }

        // the ONLY vmem in the loop: XZ(t+1) prefetch (32 KB/block)
        uint2 XZn[8];
#pragma unroll
        for (int k = 0; k < 8; ++k)
            XZn[k] = xzb[(size_t)(t + 1) * TSTRIDE + (size_t)k * 64];

#pragma unroll
        for (int nf = 0; nf < 8; ++nf) acc[nf] = (i32x4){0, 0, 0, 0};

        __builtin_amdgcn_s_setprio(1);
        // kf0,kf1 from LDS
#pragma unroll
        for (int kf = 0; kf < 2; ++kf) {
            i32x4 a = AFRAG8(hc, kf);
#pragma unroll
            for (int nf = 0; nf < 8; ++nf) {
                i32x4 b = *(const i32x4*)&UL[(((size_t)(kf * 8 + w) * 8 + nf) << 10)
                                             + (size_t)lane * 16];
                acc[nf] = __builtin_amdgcn_mfma_i32_16x16x64_i8(a, b, acc[nf], 0, 0, 0);
            }
        }
        // kf2,kf3 from AGPRs (zero memory traffic)
        {
            i32x4 a2 = AFRAG8(hc, 2);
#pragma unroll
            for (int nf = 0; nf < 8; ++nf)
                acc[nf] = __builtin_amdgcn_mfma_i32_16x16x64_i8(a2, UA2[nf], acc[nf], 0, 0, 0);
            i32x4 a3 = AFRAG8(hc, 3);
#pragma unroll
            for (int nf = 0; nf < 8; ++nf)
                acc[nf] = __builtin_amdgcn_mfma_i32_16x16x64_i8(a3, UA3[nf], acc[nf], 0, 0, 0);
        }
        __builtin_amdgcn_s_setprio(0);

        // epilogue: XZ(t) already resident
#pragma unroll
        for (int hf = 0; hf < 2; ++hf) {
#pragma unroll
            for (int j = 0; j < 4; ++j) {
                float zi = (float)acc[0 + hf][j] * d[0 + hf] + xz_at(XZ[0 + hf], j);
                float zf = (float)acc[2 + hf][j] * d[2 + hf] + xz_at(XZ[2 + hf], j);
                float zg = (float)acc[4 + hf][j] * d[4 + hf] + xz_at(XZ[4 + hf], j);
                float zo = (float)acc[6 + hf][j] * d[6 + hf] + xz_at(XZ[6 + hf], j);
                float ig = sigm(zi);
                float fg = sigm(zf);
                float gg = tanh_f(zg);
                float og = sigm(zo);
                float cn = fg * creg[hf][j] + ig * gg;
                float hv = og * tanh_f(cn);
                creg[hf][j] = cn;
                hreg[hf][j] = hv;
                int row = q * 4 + j;
                int ch  = w * 32 + hf * 16 + r16;
                hn[row * 256 + (((ch >> 4) ^ (row & 7)) << 4) + (ch & 15)] =
                    (char)__float2int_rn(hv * 127.0f);
            }
        }

        // carry prefetched XZ into next step
#pragma unroll
        for (int k = 0; k < 8; ++k) XZ[k] = XZn[k];

        // raw barrier: drain LDS h-writes only; XZ prefetch stays in flight
        asm volatile("s_waitcnt lgkmcnt(0)" ::: "memory");
        __builtin_amdgcn_s_barrier();
        cur ^= 1;
    }

    // final output from registers
#pragma unroll
    for (int hf = 0; hf < 2; ++hf) {
#pragma unroll
        for (int j = 0; j < 4; ++j) {
            int row = q * 4 + j;
            int ch  = w * 32 + hf * 16 + r16;
            size_t oi = (size_t)(row0 + row) * H_ + ch;
            outp[oi] = hreg[hf][j];
            outp[(size_t)B_ * H_ + oi] = creg[hf][j];
        }
    }
#undef AFRAG8
}

extern "C" void kernel_launch(void* const* d_in, const int* in_sizes, int n_in,
                              void* d_out, int out_size, void* d_ws, size_t ws_size,
                              hipStream_t stream) {
    const float* x    = (const float*)d_in[0];
    const float* Wm   = (const float*)d_in[1];
    const float* Um   = (const float*)d_in[2];
    const float* bias = (const float*)d_in[3];

    // ws bytes: W2 @0 (512K) | U8 @512K (256K) | scq @768K (4K) |
    //           scd @772K (4K) | xz2 @776K (210 MB)      (ws = 400 MiB)
    ushort_t* W2  = (ushort_t*)d_ws;
    char*     U8  = (char*)d_ws + 524288;
    float*    scq = (float*)((char*)d_ws + 786432);
    float*    scd = (float*)((char*)d_ws + 790528);
    ushort_t* xz2 = (ushort_t*)((char*)d_ws + 794624);

    pack_w<<<128, 256, 0, stream>>>(Wm, W2);
    pack_scale<<<256, 256, 0, stream>>>(Um, scq, scd);
    pack_u8<<<64, 256, 0, stream>>>(Um, scq, U8);
    dim3 g1(T_, 32);
    xw_gemm<<<g1, 512, 0, stream>>>(x, bias, W2, xz2);
    lstm_rec<<<128, 512, 0, stream>>>(U8, scd, xz2, (float*)d_out, T_);
}

// Round 20
// 200.596 us; speedup vs baseline: 1.1465x; 1.1172x over previous
//
#include <hip/hip_runtime.h>

// LSTM recurrence, 50 steps. B=2048, T=50, F=256, H=256, gates i,f,g,o.
// Phase 0: pack W (bf16 frag order) + quantize U to int8 (per-col scale).
// Phase 1: xz = x@W + b, BM=64 tile (unchanged).
// Phase 2: r20 -- 256 blocks x 8 rows (ALL CUs; r19 ran 128 blocks = half
//          idle). After MFMA, odd-nf (hf=1) accumulators are shuffled from
//          lanes 0-31 to lanes 32-63 (shfl lane^32 + select) so each lane
//          epilogues 4 elements, not 8: per-wave VALU+trans (the measured
//          binding term -- r19 removed the whole U stream and time didn't
//          move) halves. A-frag rows 8-15 read duplicated row&7 (LDS
//          broadcast); their MFMA outputs are discarded. U: kf0-1 LDS,
//          kf2-3 AGPR (r19). XZ(t+1) prefetch kept (4 loads/lane).

#define B_ 2048
#define T_ 50
#define F_ 256
#define H_ 256
#define NZ 1024      // 4H

typedef __attribute__((ext_vector_type(8))) short short8;
typedef __attribute__((ext_vector_type(4))) float f32x4;
typedef __attribute__((ext_vector_type(4))) int i32x4;
typedef unsigned short ushort_t;
typedef unsigned int uint_t;

__device__ __forceinline__ ushort_t f2bf(float f) {
    uint_t u = __float_as_uint(f);
    return (ushort_t)((u + 0x7FFFu + ((u >> 16) & 1u)) >> 16);
}
__device__ __forceinline__ uint_t pack2bf(float lo, float hi) {
    return (uint_t)f2bf(lo) | ((uint_t)f2bf(hi) << 16);
}
__device__ __forceinline__ float bf2f(ushort_t u) {
    return __uint_as_float(((uint_t)u) << 16);
}
__device__ __forceinline__ float sigm(float z) {
    return __builtin_amdgcn_rcpf(1.0f + __builtin_amdgcn_exp2f(z * -1.44269504f));
}
__device__ __forceinline__ float tanh_f(float z) {
    return 2.0f * __builtin_amdgcn_rcpf(1.0f + __builtin_amdgcn_exp2f(z * -2.88539008f)) - 1.0f;
}
__device__ __forceinline__ float xz_at(uint2 u, int j) {
    uint_t v = (j < 2) ? u.x : u.y;
    v = (j & 1) ? (v >> 16) : (v & 0xFFFFu);
    return bf2f((ushort_t)v);
}

// -------- pack W: fp32 [256][1024] -> bf16 frag-order panels ---------------
__global__ void pack_w(const float* __restrict__ Wm, ushort_t* __restrict__ W2) {
    int gid  = blockIdx.x * 256 + threadIdx.x;   // 32768 total
    int lane = gid & 63;
    int nf   = (gid >> 6) & 7;
    int w    = (gid >> 9) & 7;
    int kf   = (gid >> 12) & 7;
    int col = (nf >> 1) * 256 + w * 32 + (nf & 1) * 16 + (lane & 15);
    int kb  = kf * 32 + (lane >> 4) * 8;
    short8 v;
#pragma unroll
    for (int e = 0; e < 8; ++e)
        v[e] = (short)f2bf(Wm[(size_t)(kb + e) * NZ + col]);
    *(short8*)(W2 + ((((size_t)kf * 8 + w) * 8 + nf) * 64 + lane) * 8) = v;
}

// -------- U scales: per-column max, one wave per column --------------------
__global__ void pack_scale(const float* __restrict__ Um,
                           float* __restrict__ scq, float* __restrict__ scd) {
    int j    = (blockIdx.x * 256 + threadIdx.x) >> 6;   // 0..1023 (wave id)
    int lane = threadIdx.x & 63;
    float mx = 0.f;
#pragma unroll
    for (int i = 0; i < H_ / 64; ++i)
        mx = fmaxf(mx, fabsf(Um[(size_t)(i * 64 + lane) * NZ + j]));
#pragma unroll
    for (int off = 32; off; off >>= 1)
        mx = fmaxf(mx, __shfl_down(mx, off));
    if (lane == 0) {
        scq[j] = (mx > 0.f) ? (127.0f / mx) : 0.f;
        scd[j] = mx * (1.0f / 16129.0f);      // mx/127^2
    }
}

// -------- pack U: fp32 -> i8 frag order for mfma_i32_16x16x64_i8 ----------
__global__ void pack_u8(const float* __restrict__ Um,
                        const float* __restrict__ scq, char* __restrict__ U8) {
    int gid  = blockIdx.x * 256 + threadIdx.x;   // 16384 total
    int lane = gid & 63;
    int nf   = (gid >> 6) & 7;
    int w    = (gid >> 9) & 7;
    int kf   = (gid >> 12) & 3;
    int col = (nf >> 1) * 256 + w * 32 + (nf & 1) * 16 + (lane & 15);
    int k0  = kf * 64 + (lane >> 4) * 16;
    float qs = scq[col];
    union { char c[16]; int4 v; } u;
#pragma unroll
    for (int e = 0; e < 16; ++e)
        u.c[e] = (char)__float2int_rn(Um[(size_t)(k0 + e) * NZ + col] * qs);
    *(int4*)(U8 + (((size_t)(kf * 8 + w) * 8 + nf) << 10) + (size_t)lane * 16) = u.v;
}

// -------- phase 1: xz[t] = x[:,t,:] @ W + b, BM=64 (unchanged) ------------
__global__ __launch_bounds__(512, 2) void xw_gemm(
    const float* __restrict__ x, const float* __restrict__ bias,
    const ushort_t* __restrict__ W2, ushort_t* __restrict__ xz2) {
    __shared__ __align__(16) ushort_t As[64 * 256];   // 32 KB, swizzled

    const int tid = threadIdx.x;
    const int t = blockIdx.x, rb = blockIdx.y, row0 = rb * 64;
    const int w = tid >> 6, lane = tid & 63, r16 = lane & 15, q = lane >> 4;

    {
        int sr = tid >> 4, sc = tid & 15;
#pragma unroll
        for (int rr = 0; rr < 64; rr += 32) {
            const float* xp = x + ((size_t)(row0 + rr + sr) * T_ + t) * F_ + sc * 16;
            float4 f0 = *(const float4*)(xp + 0);
            float4 f1 = *(const float4*)(xp + 4);
            float4 f2 = *(const float4*)(xp + 8);
            float4 f3 = *(const float4*)(xp + 12);
            uint4 u0 = {pack2bf(f0.x, f0.y), pack2bf(f0.z, f0.w),
                        pack2bf(f1.x, f1.y), pack2bf(f1.z, f1.w)};
            uint4 u1 = {pack2bf(f2.x, f2.y), pack2bf(f2.z, f2.w),
                        pack2bf(f3.x, f3.y), pack2bf(f3.z, f3.w)};
            int c0 = (2 * sc) ^ (sr & 7), c1 = (2 * sc + 1) ^ (sr & 7);
            *(uint4*)&As[(rr + sr) * 256 + c0 * 8] = u0;
            *(uint4*)&As[(rr + sr) * 256 + c1 * 8] = u1;
        }
    }
    float bcol[8];
#pragma unroll
    for (int nf = 0; nf < 8; ++nf)
        bcol[nf] = bias[(nf >> 1) * 256 + w * 32 + (nf & 1) * 16 + r16];
    __syncthreads();

    f32x4 acc[4][8];
#pragma unroll
    for (int m = 0; m < 4; ++m)
#pragma unroll
        for (int nf = 0; nf < 8; ++nf) acc[m][nf] = (f32x4){0.f, 0.f, 0.f, 0.f};
    short8 SB0[8], SB1[8];

#define LOADB(BUF, KF_)                                                       \
    _Pragma("unroll") for (int nf = 0; nf < 8; ++nf)                          \
        BUF[nf] = *(const short8*)(W2 +                                       \
            ((((size_t)(KF_) * 8 + w) * 8 + nf) * 64 + lane) * 8);

#define MF1(BUF, KF_)                                                         \
    do {                                                                      \
        _Pragma("unroll") for (int m = 0; m < 4; ++m) {                       \
            short8 a_ = *(const short8*)&As[(m * 16 + r16) * 256              \
                                            + (((KF_)*4 + q) ^ (r16 & 7)) * 8];\
            _Pragma("unroll") for (int nf = 0; nf < 8; ++nf)                  \
                acc[m][nf] = __builtin_amdgcn_mfma_f32_16x16x32_bf16(         \
                    a_, BUF[nf], acc[m][nf], 0, 0, 0);                        \
        }                                                                     \
    } while (0)

    LOADB(SB0, 0); LOADB(SB1, 1);
    MF1(SB0, 0); LOADB(SB0, 2);
    MF1(SB1, 1); LOADB(SB1, 3);
    MF1(SB0, 2); LOADB(SB0, 4);
    MF1(SB1, 3); LOADB(SB1, 5);
    MF1(SB0, 4); LOADB(SB0, 6);
    MF1(SB1, 5); LOADB(SB1, 7);
    MF1(SB0, 6);
    MF1(SB1, 7);

    uint2* outp = (uint2*)xz2;
#pragma unroll
    for (int m = 0; m < 4; ++m) {
        const size_t cb = (((size_t)t * 64 + (size_t)(rb * 2 + (m >> 1))) * 8 + w) * 16
                        + (size_t)(m & 1) * 8;
#pragma unroll
        for (int nf = 0; nf < 8; ++nf) {
            f32x4 a = acc[m][nf];
            float b = bcol[nf];
            uint2 o = {pack2bf(a[0] + b, a[1] + b), pack2bf(a[2] + b, a[3] + b)};
            outp[(cb + nf) * 64 + lane] = o;
        }
    }
#undef LOADB
#undef MF1
}

// -------- phase 2: 256 blocks x 8 rows, lane-redistributed epilogue -------
__global__ __launch_bounds__(512, 1) void lstm_rec(
    const char* __restrict__ U8, const float* __restrict__ scd,
    const ushort_t* __restrict__ xz2, float* __restrict__ outp, int T) {
    __shared__ __align__(16) char UL[131072];     // U kf0,kf1 i8 (128 KB)
    __shared__ __align__(16) char hbc[2][2048];   // h i8 dbuf (2 x 2 KB)

    const int tid = threadIdx.x;
    const int rb = blockIdx.x;                    // 0..255 (8-row blocks)
    const int w = tid >> 6, lane = tid & 63, r16 = lane & 15;
    const int q  = lane >> 4;                     // 0..3 (k-chunk for AFRAG)
    const int hf = lane >> 5;                     // 0/1: which 16-col half
    const int q2 = (lane >> 4) & 1;               // row quad within 8 rows
    const int r8 = r16 & 7;                       // A-frag row (dup for 8-15)

    // kf0-1 -> LDS (linear 128 KB)
#pragma unroll
    for (int i = 0; i < 16; ++i) {
        int off = i * 8192 + tid * 16;
        __builtin_amdgcn_global_load_lds(
            (const __attribute__((address_space(1))) void*)(U8 + off),
            (__attribute__((address_space(3))) void*)(UL + off),
            16, 0, 0);
    }
    // h0 = 0 (2 KB, 512 threads x 4B)
    *(uint_t*)&hbc[0][tid * 4] = 0u;

    // kf2-3 -> AGPRs (64 AGPR/thread), pinned vs remat (r19-proven)
    i32x4 UA2[8], UA3[8];
#pragma unroll
    for (int nf = 0; nf < 8; ++nf)
        UA2[nf] = *(const i32x4*)(U8 + (((size_t)(2 * 8 + w) * 8 + nf) << 10)
                                  + (size_t)lane * 16);
#pragma unroll
    for (int nf = 0; nf < 8; ++nf)
        UA3[nf] = *(const i32x4*)(U8 + (((size_t)(3 * 8 + w) * 8 + nf) << 10)
                                  + (size_t)lane * 16);
#pragma unroll
    for (int nf = 0; nf < 8; ++nf) {
        asm volatile("" : "+a"(UA2[nf]));
        asm volatile("" : "+a"(UA3[nf]));
    }

    // dequant factors: 4 per lane (gate g), col = w*32 + hf*16 + r16
    const int mycol = w * 32 + hf * 16 + r16;
    float d4[4];
#pragma unroll
    for (int g = 0; g < 4; ++g) d4[g] = scd[g * 256 + mycol];

    // xz addressing: frag index (cb16 + 2g + hf)*64 + (fq*16 + r16), where
    // cb16 = ((rb>>2)*8 + w)*16 + ((rb>>1)&1)*8, fq = (rb&1)*2 + q2
    const uint2* xzp = (const uint2*)xz2;
    const size_t cb16 = (((size_t)(rb >> 2)) * 8 + w) * 16 + (size_t)((rb >> 1) & 1) * 8;
    const int fq = ((rb & 1) << 1) + q2;
    const uint2* xzb = xzp + (cb16 + hf) * 64 + fq * 16 + r16;
    const size_t TSTRIDE = (size_t)8192 * 64;     // per-t, uint2 units

#define AFRAG8(HP_, KF_)                                                      \
    (*(const i32x4*)&(HP_)[r8 * 256 + ((((KF_)*4 + q) ^ r8) << 4)])

    i32x4 acc[8];
    f32x4 creg = (f32x4){0.f, 0.f, 0.f, 0.f};
    f32x4 hreg;

    // XZ(0): 4 uint2/lane
    uint2 XZ[4];
#pragma unroll
    for (int g = 0; g < 4; ++g) XZ[g] = xzb[(size_t)g * 128];

    int cur = 0;
    __syncthreads();

#pragma clang loop unroll(disable)
    for (int t = 0; t < T; ++t) {
        const char* hc = hbc[cur];
        char* hn = hbc[cur ^ 1];

        // loop-carried AGPR pins
#pragma unroll
        for (int nf = 0; nf < 8; ++nf) {
            asm volatile("" : "+a"(UA2[nf]));
            asm volatile("" : "+a"(UA3[nf]));
        }

        // XZ(t+1) prefetch (the only loop vmem)
        uint2 XZn[4];
#pragma unroll
        for (int g = 0; g < 4; ++g)
            XZn[g] = xzb[(size_t)(t + 1) * TSTRIDE + (size_t)g * 128];

#pragma unroll
        for (int nf = 0; nf < 8; ++nf) acc[nf] = (i32x4){0, 0, 0, 0};

        __builtin_amdgcn_s_setprio(1);
#pragma unroll
        for (int kf = 0; kf < 2; ++kf) {
            i32x4 a = AFRAG8(hc, kf);
#pragma unroll
            for (int nf = 0; nf < 8; ++nf) {
                i32x4 b = *(const i32x4*)&UL[(((size_t)(kf * 8 + w) * 8 + nf) << 10)
                                             + (size_t)lane * 16];
                acc[nf] = __builtin_amdgcn_mfma_i32_16x16x64_i8(a, b, acc[nf], 0, 0, 0);
            }
        }
        {
            i32x4 a2 = AFRAG8(hc, 2);
#pragma unroll
            for (int nf = 0; nf < 8; ++nf)
                acc[nf] = __builtin_amdgcn_mfma_i32_16x16x64_i8(a2, UA2[nf], acc[nf], 0, 0, 0);
            i32x4 a3 = AFRAG8(hc, 3);
#pragma unroll
            for (int nf = 0; nf < 8; ++nf)
                acc[nf] = __builtin_amdgcn_mfma_i32_16x16x64_i8(a3, UA3[nf], acc[nf], 0, 0, 0);
        }
        __builtin_amdgcn_s_setprio(0);

        // redistribute: lanes>=32 take odd-nf acc from paired lane (lane^32);
        // each lane then owns 4 elements (gate g, its hf, rows q2*4+j).
        i32x4 sa[4];
#pragma unroll
        for (int g = 0; g < 4; ++g) {
#pragma unroll
            for (int j = 0; j < 4; ++j) {
                int other = __shfl(acc[2 * g + 1][j], lane ^ 32, 64);
                sa[g][j] = hf ? other : acc[2 * g][j];
            }
        }

        // epilogue: 4 elements/lane
#pragma unroll
        for (int j = 0; j < 4; ++j) {
            float zi = (float)sa[0][j] * d4[0] + xz_at(XZ[0], j);
            float zf = (float)sa[1][j] * d4[1] + xz_at(XZ[1], j);
            float zg = (float)sa[2][j] * d4[2] + xz_at(XZ[2], j);
            float zo = (float)sa[3][j] * d4[3] + xz_at(XZ[3], j);
            float ig = sigm(zi);
            float fg = sigm(zf);
            float gg = tanh_f(zg);
            float og = sigm(zo);
            float cn = fg * creg[j] + ig * gg;
            float hv = og * tanh_f(cn);
            creg[j] = cn;
            hreg[j] = hv;
            int row = q2 * 4 + j;                 // 0..7
            hn[row * 256 + (((mycol >> 4) ^ row) << 4) + (mycol & 15)] =
                (char)__float2int_rn(hv * 127.0f);
        }

#pragma unroll
        for (int g = 0; g < 4; ++g) XZ[g] = XZn[g];

        // raw barrier: drain LDS h-writes only; XZ prefetch stays in flight
        asm volatile("s_waitcnt lgkmcnt(0)" ::: "memory");
        __builtin_amdgcn_s_barrier();
        cur ^= 1;
    }

    // final output from registers
#pragma unroll
    for (int j = 0; j < 4; ++j) {
        int row = q2 * 4 + j;
        size_t oi = (size_t)(rb * 8 + row) * H_ + mycol;
        outp[oi] = hreg[j];
        outp[(size_t)B_ * H_ + oi] = creg[j];
    }
#undef AFRAG8
}

extern "C" void kernel_launch(void* const* d_in, const int* in_sizes, int n_in,
                              void* d_out, int out_size, void* d_ws, size_t ws_size,
                              hipStream_t stream) {
    const float* x    = (const float*)d_in[0];
    const float* Wm   = (const float*)d_in[1];
    const float* Um   = (const float*)d_in[2];
    const float* bias = (const float*)d_in[3];

    // ws bytes: W2 @0 (512K) | U8 @512K (256K) | scq @768K (4K) |
    //           scd @772K (4K) | xz2 @776K (210 MB)      (ws = 400 MiB)
    ushort_t* W2  = (ushort_t*)d_ws;
    char*     U8  = (char*)d_ws + 524288;
    float*    scq = (float*)((char*)d_ws + 786432);
    float*    scd = (float*)((char*)d_ws + 790528);
    ushort_t* xz2 = (ushort_t*)((char*)d_ws + 794624);

    pack_w<<<128, 256, 0, stream>>>(Wm, W2);
    pack_scale<<<256, 256, 0, stream>>>(Um, scq, scd);
    pack_u8<<<64, 256, 0, stream>>>(Um, scq, U8);
    dim3 g1(T_, 32);
    xw_gemm<<<g1, 512, 0, stream>>>(x, bias, W2, xz2);
    lstm_rec<<<256, 512, 0, stream>>>(U8, scd, xz2, (float*)d_out, T_);
}